// Round 17
// baseline (198.879 us; speedup 1.0000x reference)
//
#include <hip/hip_runtime.h>
#include <hip/hip_bf16.h>
#include <math.h>

#define N_NODES 32768
#define E_EDGES 262144
#define F_INF   74
#define KP      96      // padded init K
#define D0      128
#define D1      256
#define BN_EPS  1e-5f
#define RBLK    1024    // row blocks (N_NODES / 32)

#if __has_builtin(__builtin_amdgcn_cvt_pk_f32_fp8)
#define HW_FP8 1
#else
#define HW_FP8 0
#endif

typedef float f32x4 __attribute__((ext_vector_type(4)));
typedef float f32x2 __attribute__((ext_vector_type(2)));
typedef short s16x8 __attribute__((ext_vector_type(8)));

__device__ __forceinline__ float b2f(ushort h) { return __uint_as_float(((unsigned)h) << 16); }
__device__ __forceinline__ ushort f2b(float f) {
    unsigned u = __float_as_uint(f);
    return (ushort)((u + 0x7FFFu + ((u >> 16) & 1u)) >> 16);
}
// fp8 e4m3fn encode: f*2^-120 puts the e4m3 code in f32 bits 26:20.
__device__ __forceinline__ unsigned char f2q(float f) {
    unsigned u = __float_as_uint(f * 7.52316384526264005e-37f);   // 2^-120
    unsigned s = (u >> 24) & 0x80u;
    int r = (int)(((u & 0x7fffffffu) + 0x80000u) >> 20);
    r = r > 126 ? 126 : r;
    return (unsigned char)(s | (unsigned)r);
}
// fp8 e4m3fn decode (bit fallback)
__device__ __forceinline__ float q2f(unsigned x) {
    unsigned fb = ((x & 0x80u) << 24) | ((x & 0x7fu) << 20);
    return __uint_as_float(fb) * 1.32922799578491587e+36f;        // 2^120
}
// accumulate 8 fp8 (uint2) * c into a[0..7]
__device__ __forceinline__ void acc8(float* a, uint2 v, float c) {
#if HW_FP8
    f32x2 p;
    p = __builtin_amdgcn_cvt_pk_f32_fp8((int)v.x, false); a[0] += p[0] * c; a[1] += p[1] * c;
    p = __builtin_amdgcn_cvt_pk_f32_fp8((int)v.x, true);  a[2] += p[0] * c; a[3] += p[1] * c;
    p = __builtin_amdgcn_cvt_pk_f32_fp8((int)v.y, false); a[4] += p[0] * c; a[5] += p[1] * c;
    p = __builtin_amdgcn_cvt_pk_f32_fp8((int)v.y, true);  a[6] += p[0] * c; a[7] += p[1] * c;
#else
    unsigned d;
    d = v.x; a[0] += q2f(d & 255u) * c; a[1] += q2f((d >> 8) & 255u) * c;
             a[2] += q2f((d >> 16) & 255u) * c; a[3] += q2f(d >> 24) * c;
    d = v.y; a[4] += q2f(d & 255u) * c; a[5] += q2f((d >> 8) & 255u) * c;
             a[6] += q2f((d >> 16) & 255u) * c; a[7] += q2f(d >> 24) * c;
#endif
}
__device__ __forceinline__ float gelu_exact(float x) {
    return 0.5f * x * (1.0f + erff(x * 0.70710678118654752440f));
}

// ---------- front A: degree counts + weight/bf16 prep (independent jobs) ----------

__global__ void k_front_a(const int* __restrict__ src, const int* __restrict__ dst,
                          int* __restrict__ deg,
                          const float* __restrict__ nf, const float* __restrict__ Wi,
                          const float* __restrict__ w1, const float* __restrict__ rw,
                          const float* __restrict__ w2,
                          ushort* __restrict__ nfB, ushort* __restrict__ WTB,
                          ushort* __restrict__ WB1, ushort* __restrict__ RWB,
                          ushort* __restrict__ WB2) {
    int bid = blockIdx.x;
    int tid = threadIdx.x;
    if (bid < 1024) {           // degrees: 1024 * 256 = E
        int e = bid * 256 + tid;
        atomicAdd(&deg[src[e]], 1);
        atomicAdd(&deg[N_NODES + dst[e]], 1);
        return;
    }
    int idx = (bid - 1024) * 256 + tid;   // N*96 threads
    {
        int n = idx / KP, k = idx - n * KP;
        nfB[idx] = (k < F_INF) ? f2b(nf[n * F_INF + k]) : (ushort)0;
    }
    if (idx < D0 * KP) {
        int c = idx / KP, k = idx - c * KP;
        WTB[idx] = (k < F_INF) ? f2b(Wi[c * F_INF + k]) : (ushort)0;
    }
    if (idx < D1 * D0) {
        int n = idx >> 7, k = idx & 127;
        WB1[idx] = f2b(w1[k * D1 + n]);
        RWB[idx] = f2b(rw[idx]);
    }
    if (idx < D1 * D1) {
        int n = idx >> 8, k = idx & 255;
        WB2[idx] = f2b(w2[k * D1 + n]);
    }
}

// scan in-degrees -> row_off; also rsq factors; also zero cursor
__global__ __launch_bounds__(1024) void k_scan(const int* __restrict__ deg,
                                               int* __restrict__ row_off,
                                               float* __restrict__ rsq_out,
                                               float* __restrict__ rsq_in,
                                               int* __restrict__ cursor) {
    __shared__ int part[1024];
    int t = threadIdx.x;
    int base = t * 32;
    int loc[32];
    int s = 0;
    #pragma unroll
    for (int i = 0; i < 32; i++) { loc[i] = s; s += deg[N_NODES + base + i]; }
    part[t] = s;
    #pragma unroll
    for (int i = 0; i < 32; i++) {
        int n = base + i;
        int d_o = deg[n];           if (d_o < 1) d_o = 1;
        int d_i = deg[N_NODES + n]; if (d_i < 1) d_i = 1;
        rsq_out[n] = 1.0f / sqrtf((float)d_o);
        rsq_in[n]  = 1.0f / sqrtf((float)d_i);
        cursor[n] = 0;
    }
    __syncthreads();
    for (int off = 1; off < 1024; off <<= 1) {
        int v = 0;
        if (t >= off) v = part[t - off];
        __syncthreads();
        if (t >= off) part[t] += v;
        __syncthreads();
    }
    int pre = (t == 0) ? 0 : part[t - 1];
    #pragma unroll
    for (int i = 0; i < 32; i++) row_off[base + i] = pre + loc[i];
    if (t == 1023) row_off[N_NODES] = part[1023];
}

// ---------- front B: CSR fill + init MFMA (independent jobs), 512-thr blocks ----------
// Edge record packed: csr[pos] = {src, bits(rsq_out[src])}.

__global__ __launch_bounds__(512) void k_front_b(
    const int* __restrict__ src, const int* __restrict__ dst,
    const int* __restrict__ row_off, const float* __restrict__ rsq_out,
    int* __restrict__ cursor, int2* __restrict__ csr,
    const ushort* __restrict__ nfB, const ushort* __restrict__ WTB,
    ushort* __restrict__ h0) {
    int bid = blockIdx.x;
    int tid = threadIdx.x;
    if (bid < 512) {            // fill: 512 * 512 = E
        int e = bid * 512 + tid;
        int d = dst[e];
        int s = src[e];
        int slot = atomicAdd(&cursor[d], 1);
        int pos = row_off[d] + slot;
        csr[pos] = make_int2(s, __float_as_int(rsq_out[s]));
        return;
    }
    // init MFMA: h0 = nfB @ WTB^T, 16 rows/block, 8 waves x 16 cols
    int b2 = bid - 512;         // 0..2047
    int w = tid >> 6, lane = tid & 63, m = lane & 15, g4 = lane >> 4;
    int col = w * 16 + m;
    int rbase = b2 * 16;
    s16x8 B[3], A[3];
    #pragma unroll
    for (int j = 0; j < 3; j++)
        B[j] = *reinterpret_cast<const s16x8*>(&WTB[(size_t)col * KP + j * 32 + g4 * 8]);
    #pragma unroll
    for (int j = 0; j < 3; j++)
        A[j] = *reinterpret_cast<const s16x8*>(&nfB[(size_t)(rbase + m) * KP + j * 32 + g4 * 8]);
    f32x4 acc = (f32x4){0.f, 0.f, 0.f, 0.f};
    #pragma unroll
    for (int j = 0; j < 3; j++)
        acc = __builtin_amdgcn_mfma_f32_16x16x32_bf16(A[j], B[j], acc, 0, 0, 0);
    #pragma unroll
    for (int r = 0; r < 4; r++)
        h0[(size_t)(rbase + g4 * 4 + r) * D0 + col] = f2b(acc[r]);
}

// ---------- layer1 fused: 512 thr, 32 rows/block, edge-split-2 bf16 gather->LDS, MFMA ----------
// Gather: 16 thr/node = 2 edge-halves x 8 col-threads; thread covers cols [f,f+8) and [f+64,f+72).
// Halves combine via shfl_xor(8) (same wave).   [round-15 body — measured best]

__global__ __launch_bounds__(512) void k_layer1f(
    const ushort* __restrict__ h0B, const float* __restrict__ rsq_in,
    const int* __restrict__ row_off, const int2* __restrict__ csr,
    const ushort* __restrict__ WB1, const ushort* __restrict__ RWB,
    const float* __restrict__ b1, const float* __restrict__ rb,
    ushort* __restrict__ t1B, unsigned char* __restrict__ t1Q,
    float* __restrict__ partials) {
    __shared__ ushort sA[32 * 128];
    int tid = threadIdx.x;
    int rbase = blockIdx.x * 32;
    // ---- gather phase ----
    {
        int nloc = tid >> 4;
        int half = (tid >> 3) & 1;
        int node = rbase + nloc;
        int f = (tid & 7) * 8;         // cols [f,f+8) and [f+64,f+72)
        int beg = row_off[node], end = row_off[node + 1];
        float a0[8], a1[8];
        #pragma unroll
        for (int j = 0; j < 8; j++) { a0[j] = 0.f; a1[j] = 0.f; }
        int e = beg + half;
        for (; e + 6 < end; e += 8) {
            int2 r0 = csr[e], r1 = csr[e + 2], r2 = csr[e + 4], r3 = csr[e + 6];
            float c0 = __int_as_float(r0.y), c1 = __int_as_float(r1.y);
            float c2 = __int_as_float(r2.y), c3 = __int_as_float(r3.y);
            s16x8 v00 = *reinterpret_cast<const s16x8*>(&h0B[(size_t)r0.x * D0 + f]);
            s16x8 v01 = *reinterpret_cast<const s16x8*>(&h0B[(size_t)r0.x * D0 + f + 64]);
            s16x8 v10 = *reinterpret_cast<const s16x8*>(&h0B[(size_t)r1.x * D0 + f]);
            s16x8 v11 = *reinterpret_cast<const s16x8*>(&h0B[(size_t)r1.x * D0 + f + 64]);
            s16x8 v20 = *reinterpret_cast<const s16x8*>(&h0B[(size_t)r2.x * D0 + f]);
            s16x8 v21 = *reinterpret_cast<const s16x8*>(&h0B[(size_t)r2.x * D0 + f + 64]);
            s16x8 v30 = *reinterpret_cast<const s16x8*>(&h0B[(size_t)r3.x * D0 + f]);
            s16x8 v31 = *reinterpret_cast<const s16x8*>(&h0B[(size_t)r3.x * D0 + f + 64]);
            #pragma unroll
            for (int j = 0; j < 8; j++) {
                a0[j] += b2f((ushort)v00[j]) * c0 + b2f((ushort)v10[j]) * c1 +
                         b2f((ushort)v20[j]) * c2 + b2f((ushort)v30[j]) * c3;
                a1[j] += b2f((ushort)v01[j]) * c0 + b2f((ushort)v11[j]) * c1 +
                         b2f((ushort)v21[j]) * c2 + b2f((ushort)v31[j]) * c3;
            }
        }
        for (; e < end; e += 2) {
            int2 r = csr[e];
            float sc = __int_as_float(r.y);
            s16x8 v0 = *reinterpret_cast<const s16x8*>(&h0B[(size_t)r.x * D0 + f]);
            s16x8 v1 = *reinterpret_cast<const s16x8*>(&h0B[(size_t)r.x * D0 + f + 64]);
            #pragma unroll
            for (int j = 0; j < 8; j++) {
                a0[j] += b2f((ushort)v0[j]) * sc;
                a1[j] += b2f((ushort)v1[j]) * sc;
            }
        }
        #pragma unroll
        for (int j = 0; j < 8; j++) {
            a0[j] += __shfl_xor(a0[j], 8);
            a1[j] += __shfl_xor(a1[j], 8);
        }
        if (half == 0) {
            float si = rsq_in[node];
            s16x8 o0, o1;
            #pragma unroll
            for (int j = 0; j < 8; j++) {
                o0[j] = (short)f2b(a0[j] * si);
                o1[j] = (short)f2b(a1[j] * si);
            }
            int swz = (nloc & 15) << 4;
            int x0 = f * 2;
            *reinterpret_cast<s16x8*>(((char*)sA) + nloc * 256 + (x0 ^ swz)) = o0;
            *reinterpret_cast<s16x8*>(((char*)sA) + nloc * 256 + ((x0 + 128) ^ swz)) = o1;
        }
    }
    __syncthreads();
    // ---- MFMA phase ----
    int w = tid >> 6, lane = tid & 63, m = lane & 15, g4 = lane >> 4;
    int cb = w * 32;
    s16x8 BG[2][4], BR[2][4];
    #pragma unroll
    for (int nt = 0; nt < 2; nt++)
        #pragma unroll
        for (int j = 0; j < 4; j++) {
            BG[nt][j] = *reinterpret_cast<const s16x8*>(&WB1[(size_t)(cb + nt * 16 + m) * D0 + j * 32 + g4 * 8]);
            BR[nt][j] = *reinterpret_cast<const s16x8*>(&RWB[(size_t)(cb + nt * 16 + m) * D0 + j * 32 + g4 * 8]);
        }
    float bg[2], brv[2];
    #pragma unroll
    for (int nt = 0; nt < 2; nt++) {
        bg[nt]  = b1[cb + nt * 16 + m];
        brv[nt] = rb[cb + nt * 16 + m];
    }
    float ps[2] = {0.f, 0.f}, pq[2] = {0.f, 0.f};
    #pragma unroll
    for (int rt = 0; rt < 2; rt++) {
        int row = rt * 16 + m;
        s16x8 aA[4], aH[4];
        #pragma unroll
        for (int j = 0; j < 4; j++) {
            int boff = row * 256 + (((j * 4 + g4) * 16) ^ ((row & 15) << 4));
            aA[j] = *reinterpret_cast<const s16x8*>(((const char*)sA) + boff);
            aH[j] = *reinterpret_cast<const s16x8*>(&h0B[(size_t)(rbase + row) * D0 + j * 32 + g4 * 8]);
        }
        f32x4 accG[2], accR[2];
        #pragma unroll
        for (int nt = 0; nt < 2; nt++) {
            accG[nt] = (f32x4){0.f, 0.f, 0.f, 0.f};
            accR[nt] = (f32x4){0.f, 0.f, 0.f, 0.f};
        }
        #pragma unroll
        for (int j = 0; j < 4; j++)
            #pragma unroll
            for (int nt = 0; nt < 2; nt++) {
                accG[nt] = __builtin_amdgcn_mfma_f32_16x16x32_bf16(aA[j], BG[nt][j], accG[nt], 0, 0, 0);
                accR[nt] = __builtin_amdgcn_mfma_f32_16x16x32_bf16(aH[j], BR[nt][j], accR[nt], 0, 0, 0);
            }
        #pragma unroll
        for (int nt = 0; nt < 2; nt++) {
            int col = cb + nt * 16 + m;
            #pragma unroll
            for (int r = 0; r < 4; r++) {
                int orow = rbase + rt * 16 + g4 * 4 + r;
                float v = gelu_exact(accG[nt][r] + bg[nt]) + accR[nt][r] + brv[nt];
                t1B[(size_t)orow * D1 + col] = f2b(v);
                t1Q[(size_t)orow * D1 + col] = f2q(v);
                ps[nt] += v; pq[nt] += v * v;
            }
        }
    }
    #pragma unroll
    for (int nt = 0; nt < 2; nt++) {
        float s = ps[nt], q = pq[nt];
        s += __shfl_xor(s, 16); s += __shfl_xor(s, 32);
        q += __shfl_xor(q, 16); q += __shfl_xor(q, 32);
        if (g4 == 0) {
            int col = cb + nt * 16 + m;
            partials[(size_t)col * RBLK + blockIdx.x] = s;
            partials[(size_t)(256 + col) * RBLK + blockIdx.x] = q;
        }
    }
}

// ---------- layer2 fused: 1024 thr, 32 rows/block, shfl-batched fp8 gather, MFMA ----------
// Gather: 32 thr/node, each owns one 8-col fp8 chunk (8B); all threads walk all edges
// via shfl broadcast of the node's first 32 edge records.  [round-16 body — measured best]

__global__ __launch_bounds__(1024) void k_layer2f(
    const ushort* __restrict__ t1B, const unsigned char* __restrict__ t1Q,
    const float* __restrict__ sc1, const float* __restrict__ sh1,
    const float* __restrict__ rsq_in,
    const int* __restrict__ row_off, const int2* __restrict__ csr,
    const ushort* __restrict__ WB2, const float* __restrict__ b2,
    ushort* __restrict__ t2B, float* __restrict__ partials) {
    __shared__ ushort sA[32 * 256];
    int tid = threadIdx.x;
    int rbase = blockIdx.x * 32;
    // ---- gather phase ----
    {
        int nloc = tid >> 5;
        int l32 = tid & 31;
        int node = rbase + nloc;
        int f0 = l32 * 8;              // fp8 cols [f0, f0+8)
        int beg = row_off[node], end = row_off[node + 1];
        int deg = end - beg;
        int grp = (tid & 63) & 32;     // node's base lane within wave
        float a[8];
        #pragma unroll
        for (int j = 0; j < 8; j++) a[j] = 0.f;
        float ssum = 0.f;
        int2 my = (l32 < deg) ? csr[beg + l32] : make_int2(0, 0);
        int nb = deg < 32 ? deg : 32;
        for (int kb = 0; kb < nb; kb += 8) {
            int s[8]; float c[8];
            #pragma unroll
            for (int k2 = 0; k2 < 8; k2++) {
                s[k2] = __shfl(my.x, grp + kb + k2);
                c[k2] = __int_as_float(__shfl(my.y, grp + kb + k2));
            }
            uint2 q[8];
            #pragma unroll
            for (int k2 = 0; k2 < 8; k2++)
                q[k2] = *reinterpret_cast<const uint2*>(&t1Q[(size_t)s[k2] * D1 + f0]);
            #pragma unroll
            for (int k2 = 0; k2 < 8; k2++) {
                acc8(a, q[k2], c[k2]);
                ssum += c[k2];
            }
        }
        for (int e = beg + 32; e < end; e++) {      // essentially never
            int2 r = csr[e];
            float sc = __int_as_float(r.y);
            uint2 q = *reinterpret_cast<const uint2*>(&t1Q[(size_t)r.x * D1 + f0]);
            ssum += sc;
            acc8(a, q, sc);
        }
        float si = rsq_in[node];
        s16x8 o;
        #pragma unroll
        for (int j = 0; j < 8; j++)
            o[j] = (short)f2b((sc1[f0 + j] * a[j] + sh1[f0 + j] * ssum) * si);
        int swz = (nloc & 15) << 4;
        int boff = nloc * 512 + ((f0 * 2) ^ swz);
        *reinterpret_cast<s16x8*>(((char*)sA) + boff) = o;
    }
    __syncthreads();
    // ---- MFMA phase: 16 waves x 16 cols, 2 row-tiles each ----
    int w = tid >> 6, lane = tid & 63, m = lane & 15, g4 = lane >> 4;
    int col = w * 16 + m;
    ushort rres[2][4];
    #pragma unroll
    for (int rt = 0; rt < 2; rt++)
        #pragma unroll
        for (int r = 0; r < 4; r++)
            rres[rt][r] = t1B[(size_t)(rbase + rt * 16 + g4 * 4 + r) * D1 + col];
    s16x8 BG[8];
    #pragma unroll
    for (int j = 0; j < 8; j++)
        BG[j] = *reinterpret_cast<const s16x8*>(&WB2[(size_t)col * D1 + j * 32 + g4 * 8]);
    float bg = b2[col], a1c = sc1[col], s1c = sh1[col];
    float ps = 0.f, pq = 0.f;
    #pragma unroll
    for (int rt = 0; rt < 2; rt++) {
        int row = rt * 16 + m;
        s16x8 aA[8];
        #pragma unroll
        for (int j = 0; j < 8; j++) {
            int boff = row * 512 + (((j * 4 + g4) * 16) ^ ((row & 15) << 4));
            aA[j] = *reinterpret_cast<const s16x8*>(((const char*)sA) + boff);
        }
        f32x4 acc = (f32x4){0.f, 0.f, 0.f, 0.f};
        #pragma unroll
        for (int j = 0; j < 8; j++)
            acc = __builtin_amdgcn_mfma_f32_16x16x32_bf16(aA[j], BG[j], acc, 0, 0, 0);
        #pragma unroll
        for (int r = 0; r < 4; r++) {
            int orow = rbase + rt * 16 + g4 * 4 + r;
            float h1v = fmaf(b2f(rres[rt][r]), a1c, s1c);
            float v = gelu_exact(acc[r] + bg) + h1v;
            t2B[(size_t)orow * D1 + col] = f2b(v);
            ps += v; pq += v * v;
        }
    }
    ps += __shfl_xor(ps, 16); ps += __shfl_xor(ps, 32);
    pq += __shfl_xor(pq, 16); pq += __shfl_xor(pq, 32);
    if (g4 == 0) {
        partials[(size_t)col * RBLK + blockIdx.x] = ps;
        partials[(size_t)(256 + col) * RBLK + blockIdx.x] = pq;
    }
}

// ---------- BN reduce: one block per channel ----------

__global__ __launch_bounds__(256) void k_reduce(
    const float* __restrict__ partials, const float* __restrict__ g,
    const float* __restrict__ b, float* __restrict__ sc, float* __restrict__ sh) {
    int c = blockIdx.x;
    int t = threadIdx.x;
    const float* ps = partials + (size_t)c * RBLK;
    const float* pq = partials + (size_t)(256 + c) * RBLK;
    float s = ps[t] + ps[t + 256] + ps[t + 512] + ps[t + 768];
    float q = pq[t] + pq[t + 256] + pq[t + 512] + pq[t + 768];
    __shared__ float Ls[256], Lq[256];
    Ls[t] = s; Lq[t] = q;
    __syncthreads();
    for (int o = 128; o > 0; o >>= 1) {
        if (t < o) { Ls[t] += Ls[t + o]; Lq[t] += Lq[t + o]; }
        __syncthreads();
    }
    if (t == 0) {
        float m = Ls[0] * (1.0f / (float)N_NODES);
        float var = Lq[0] * (1.0f / (float)N_NODES) - m * m;
        float a = g[c] / sqrtf(var + BN_EPS);
        sc[c] = a;
        sh[c] = b[c] - m * a;
    }
}

// ---------- final BN apply: out = sc2*t2 + sh2  (fp32 out) ----------

__global__ __launch_bounds__(256) void k_apply(
    const ushort* __restrict__ t2B, const float* __restrict__ sc,
    const float* __restrict__ sh, float* __restrict__ out) {
    int idx = blockIdx.x * 256 + threadIdx.x;
    size_t base = (size_t)idx * 8;
    int c = (int)(base & 255);
    s16x8 v = *reinterpret_cast<const s16x8*>(&t2B[base]);
    float4 o0, o1;
    o0.x = fmaf(b2f((ushort)v[0]), sc[c + 0], sh[c + 0]);
    o0.y = fmaf(b2f((ushort)v[1]), sc[c + 1], sh[c + 1]);
    o0.z = fmaf(b2f((ushort)v[2]), sc[c + 2], sh[c + 2]);
    o0.w = fmaf(b2f((ushort)v[3]), sc[c + 3], sh[c + 3]);
    o1.x = fmaf(b2f((ushort)v[4]), sc[c + 4], sh[c + 4]);
    o1.y = fmaf(b2f((ushort)v[5]), sc[c + 5], sh[c + 5]);
    o1.z = fmaf(b2f((ushort)v[6]), sc[c + 6], sh[c + 6]);
    o1.w = fmaf(b2f((ushort)v[7]), sc[c + 7], sh[c + 7]);
    *reinterpret_cast<float4*>(&out[base]) = o0;
    *reinterpret_cast<float4*>(&out[base + 4]) = o1;
}

// ---------- launch ----------

static inline size_t align256(size_t x) { return (x + 255) & ~(size_t)255; }

extern "C" void kernel_launch(void* const* d_in, const int* in_sizes, int n_in,
                              void* d_out, int out_size, void* d_ws, size_t ws_size,
                              hipStream_t stream) {
    const float* node_feats = (const float*)d_in[0];
    const float* W_init     = (const float*)d_in[1];
    const float* gcn_w1     = (const float*)d_in[2];
    const float* gcn_b1     = (const float*)d_in[3];
    const float* res_w1     = (const float*)d_in[4];
    const float* res_b1     = (const float*)d_in[5];
    const float* bn_g1      = (const float*)d_in[6];
    const float* bn_b1      = (const float*)d_in[7];
    const float* gcn_w2     = (const float*)d_in[8];
    const float* gcn_b2     = (const float*)d_in[9];
    const float* bn_g2      = (const float*)d_in[10];
    const float* bn_b2      = (const float*)d_in[11];
    const int*   edge_src   = (const int*)d_in[12];
    const int*   edge_dst   = (const int*)d_in[13];
    float* out = (float*)d_out;

    char* p = (char*)d_ws;
    size_t off = 0;
    auto take = [&](size_t bytes) { void* r = p + off; off += align256(bytes); return r; };

    ushort* h0B   = (ushort*)take((size_t)N_NODES * D0 * 2);
    ushort* t1B   = (ushort*)take((size_t)N_NODES * D1 * 2);
    unsigned char* t1Q = (unsigned char*)take((size_t)N_NODES * D1);
    ushort* t2B   = (ushort*)take((size_t)N_NODES * D1 * 2);
    ushort* nfB   = (ushort*)take((size_t)N_NODES * KP * 2);
    ushort* WTB   = (ushort*)take((size_t)D0 * KP * 2);
    ushort* WB1   = (ushort*)take((size_t)D1 * D0 * 2);
    ushort* RWB   = (ushort*)take((size_t)D1 * D0 * 2);
    ushort* WB2   = (ushort*)take((size_t)D1 * D1 * 2);
    float*  part1 = (float*)take((size_t)2 * 256 * RBLK * 4);
    float*  part2 = (float*)take((size_t)2 * 256 * RBLK * 4);
    float*  sc1   = (float*)take(256 * 4);
    float*  sh1   = (float*)take(256 * 4);
    float*  sc2   = (float*)take(256 * 4);
    float*  sh2   = (float*)take(256 * 4);
    float*  rsq_out = (float*)take((size_t)N_NODES * 4);
    float*  rsq_in  = (float*)take((size_t)N_NODES * 4);
    int*    degi    = (int*)take((size_t)2 * N_NODES * 4);
    int*    cursor  = (int*)take((size_t)N_NODES * 4);
    int*    row_off = (int*)take((size_t)(N_NODES + 2) * 4);
    int2*   csr     = (int2*)take((size_t)E_EDGES * 8);

    hipMemsetAsync(degi, 0, (size_t)2 * N_NODES * 4, stream);

    k_front_a<<<1024 + (N_NODES * KP) / 256, 256, 0, stream>>>(
        edge_src, edge_dst, degi, node_feats, W_init, gcn_w1, res_w1, gcn_w2,
        nfB, WTB, WB1, RWB, WB2);

    k_scan<<<1, 1024, 0, stream>>>(degi, row_off, rsq_out, rsq_in, cursor);

    k_front_b<<<512 + N_NODES / 16, 512, 0, stream>>>(
        edge_src, edge_dst, row_off, rsq_out, cursor, csr, nfB, WTB, h0B);

    k_layer1f<<<RBLK, 512, 0, stream>>>(h0B, rsq_in, row_off, csr,
                                        WB1, RWB, gcn_b1, res_b1, t1B, t1Q, part1);
    k_reduce<<<256, 256, 0, stream>>>(part1, bn_g1, bn_b1, sc1, sh1);

    k_layer2f<<<RBLK, 1024, 0, stream>>>(t1B, t1Q, sc1, sh1, rsq_in, row_off, csr,
                                         WB2, gcn_b2, t2B, part2);
    k_reduce<<<256, 256, 0, stream>>>(part2, bn_g2, bn_b2, sc2, sh2);

    k_apply<<<(N_NODES * D1 / 8) / 256, 256, 0, stream>>>(t2B, sc2, sh2, out);
}

// Round 18
// 195.051 us; speedup vs baseline: 1.0196x; 1.0196x over previous
//
#include <hip/hip_runtime.h>
#include <hip/hip_bf16.h>
#include <math.h>

#define N_NODES 32768
#define E_EDGES 262144
#define F_INF   74
#define KP      96      // padded init K
#define D0      128
#define D1      256
#define BN_EPS  1e-5f
#define RBLK    1024    // row blocks (N_NODES / 32)

#if __has_builtin(__builtin_amdgcn_cvt_pk_f32_fp8)
#define HW_FP8 1
#else
#define HW_FP8 0
#endif

typedef float f32x4 __attribute__((ext_vector_type(4)));
typedef float f32x2 __attribute__((ext_vector_type(2)));
typedef short s16x8 __attribute__((ext_vector_type(8)));

__device__ __forceinline__ float b2f(ushort h) { return __uint_as_float(((unsigned)h) << 16); }
__device__ __forceinline__ ushort f2b(float f) {
    unsigned u = __float_as_uint(f);
    return (ushort)((u + 0x7FFFu + ((u >> 16) & 1u)) >> 16);
}
// fp8 e4m3fn encode: f*2^-120 puts the e4m3 code in f32 bits 26:20.
__device__ __forceinline__ unsigned char f2q(float f) {
    unsigned u = __float_as_uint(f * 7.52316384526264005e-37f);   // 2^-120
    unsigned s = (u >> 24) & 0x80u;
    int r = (int)(((u & 0x7fffffffu) + 0x80000u) >> 20);
    r = r > 126 ? 126 : r;
    return (unsigned char)(s | (unsigned)r);
}
// fp8 e4m3fn decode (bit fallback)
__device__ __forceinline__ float q2f(unsigned x) {
    unsigned fb = ((x & 0x80u) << 24) | ((x & 0x7fu) << 20);
    return __uint_as_float(fb) * 1.32922799578491587e+36f;        // 2^120
}
// accumulate 8 fp8 (uint2) * c into a[0..7]
__device__ __forceinline__ void acc8(float* a, uint2 v, float c) {
#if HW_FP8
    f32x2 p;
    p = __builtin_amdgcn_cvt_pk_f32_fp8((int)v.x, false); a[0] += p[0] * c; a[1] += p[1] * c;
    p = __builtin_amdgcn_cvt_pk_f32_fp8((int)v.x, true);  a[2] += p[0] * c; a[3] += p[1] * c;
    p = __builtin_amdgcn_cvt_pk_f32_fp8((int)v.y, false); a[4] += p[0] * c; a[5] += p[1] * c;
    p = __builtin_amdgcn_cvt_pk_f32_fp8((int)v.y, true);  a[6] += p[0] * c; a[7] += p[1] * c;
#else
    unsigned d;
    d = v.x; a[0] += q2f(d & 255u) * c; a[1] += q2f((d >> 8) & 255u) * c;
             a[2] += q2f((d >> 16) & 255u) * c; a[3] += q2f(d >> 24) * c;
    d = v.y; a[4] += q2f(d & 255u) * c; a[5] += q2f((d >> 8) & 255u) * c;
             a[6] += q2f((d >> 16) & 255u) * c; a[7] += q2f(d >> 24) * c;
#endif
}
__device__ __forceinline__ float gelu_exact(float x) {
    return 0.5f * x * (1.0f + erff(x * 0.70710678118654752440f));
}

// ---------- front A: degree counts + weight/bf16 prep (independent jobs) ----------

__global__ void k_front_a(const int* __restrict__ src, const int* __restrict__ dst,
                          int* __restrict__ deg,
                          const float* __restrict__ nf, const float* __restrict__ Wi,
                          const float* __restrict__ w1, const float* __restrict__ rw,
                          const float* __restrict__ w2,
                          ushort* __restrict__ nfB, ushort* __restrict__ WTB,
                          ushort* __restrict__ WB1, ushort* __restrict__ RWB,
                          ushort* __restrict__ WB2) {
    int bid = blockIdx.x;
    int tid = threadIdx.x;
    if (bid < 1024) {           // degrees: 1024 * 256 = E
        int e = bid * 256 + tid;
        atomicAdd(&deg[src[e]], 1);
        atomicAdd(&deg[N_NODES + dst[e]], 1);
        return;
    }
    int idx = (bid - 1024) * 256 + tid;   // N*96 threads
    {
        int n = idx / KP, k = idx - n * KP;
        nfB[idx] = (k < F_INF) ? f2b(nf[n * F_INF + k]) : (ushort)0;
    }
    if (idx < D0 * KP) {
        int c = idx / KP, k = idx - c * KP;
        WTB[idx] = (k < F_INF) ? f2b(Wi[c * F_INF + k]) : (ushort)0;
    }
    if (idx < D1 * D0) {
        int n = idx >> 7, k = idx & 127;
        WB1[idx] = f2b(w1[k * D1 + n]);
        RWB[idx] = f2b(rw[idx]);
    }
    if (idx < D1 * D1) {
        int n = idx >> 8, k = idx & 255;
        WB2[idx] = f2b(w2[k * D1 + n]);
    }
}

// ---------- scan + init MFMA combined: block 0 scans, blocks 1.. run init GEMM ----------
// Fills the single-block scan's serial bubble with the h0 GEMM (dep: nfB/WTB only).

__global__ __launch_bounds__(1024) void k_scan_init(
    const int* __restrict__ deg,
    int* __restrict__ row_off, float* __restrict__ rsq_out,
    float* __restrict__ rsq_in, int* __restrict__ cursor,
    const ushort* __restrict__ nfB, const ushort* __restrict__ WTB,
    ushort* __restrict__ h0) {
    int t = threadIdx.x;
    if (blockIdx.x == 0) {
        __shared__ int part[1024];
        int base = t * 32;
        int loc[32];
        int s = 0;
        #pragma unroll
        for (int i = 0; i < 32; i++) { loc[i] = s; s += deg[N_NODES + base + i]; }
        part[t] = s;
        #pragma unroll
        for (int i = 0; i < 32; i++) {
            int n = base + i;
            int d_o = deg[n];           if (d_o < 1) d_o = 1;
            int d_i = deg[N_NODES + n]; if (d_i < 1) d_i = 1;
            rsq_out[n] = 1.0f / sqrtf((float)d_o);
            rsq_in[n]  = 1.0f / sqrtf((float)d_i);
            cursor[n] = 0;
        }
        __syncthreads();
        for (int off = 1; off < 1024; off <<= 1) {
            int v = 0;
            if (t >= off) v = part[t - off];
            __syncthreads();
            if (t >= off) part[t] += v;
            __syncthreads();
        }
        int pre = (t == 0) ? 0 : part[t - 1];
        #pragma unroll
        for (int i = 0; i < 32; i++) row_off[base + i] = pre + loc[i];
        if (t == 1023) row_off[N_NODES] = part[1023];
        return;
    }
    // init MFMA: h0 = nfB @ WTB^T; 32 rows/block, 16 waves (2 row-groups x 8 col-waves)
    int b2 = blockIdx.x - 1;       // 0..1023
    int w = t >> 6, lane = t & 63, m = lane & 15, g4 = lane >> 4;
    int col = (w & 7) * 16 + m;
    int rbase = b2 * 32 + (w >> 3) * 16;
    s16x8 B[3], A[3];
    #pragma unroll
    for (int j = 0; j < 3; j++)
        B[j] = *reinterpret_cast<const s16x8*>(&WTB[(size_t)col * KP + j * 32 + g4 * 8]);
    #pragma unroll
    for (int j = 0; j < 3; j++)
        A[j] = *reinterpret_cast<const s16x8*>(&nfB[(size_t)(rbase + m) * KP + j * 32 + g4 * 8]);
    f32x4 acc = (f32x4){0.f, 0.f, 0.f, 0.f};
    #pragma unroll
    for (int j = 0; j < 3; j++)
        acc = __builtin_amdgcn_mfma_f32_16x16x32_bf16(A[j], B[j], acc, 0, 0, 0);
    #pragma unroll
    for (int r = 0; r < 4; r++)
        h0[(size_t)(rbase + g4 * 4 + r) * D0 + col] = f2b(acc[r]);
}

// ---------- fill: CSR build (packed edge records) ----------

__global__ __launch_bounds__(512) void k_fill(
    const int* __restrict__ src, const int* __restrict__ dst,
    const int* __restrict__ row_off, const float* __restrict__ rsq_out,
    int* __restrict__ cursor, int2* __restrict__ csr) {
    int e = blockIdx.x * 512 + threadIdx.x;
    int d = dst[e];
    int s = src[e];
    int slot = atomicAdd(&cursor[d], 1);
    int pos = row_off[d] + slot;
    csr[pos] = make_int2(s, __float_as_int(rsq_out[s]));
}

// ---------- layer1 fused: 512 thr, 32 rows/block, edge-split-2 bf16 gather->LDS, MFMA ----------
// Gather: 16 thr/node = 2 edge-halves x 8 col-threads; thread covers cols [f,f+8) and [f+64,f+72).
// Halves combine via shfl_xor(8) (same wave).   [round-15 body — measured best]

__global__ __launch_bounds__(512) void k_layer1f(
    const ushort* __restrict__ h0B, const float* __restrict__ rsq_in,
    const int* __restrict__ row_off, const int2* __restrict__ csr,
    const ushort* __restrict__ WB1, const ushort* __restrict__ RWB,
    const float* __restrict__ b1, const float* __restrict__ rb,
    ushort* __restrict__ t1B, unsigned char* __restrict__ t1Q,
    float* __restrict__ partials) {
    __shared__ ushort sA[32 * 128];
    int tid = threadIdx.x;
    int rbase = blockIdx.x * 32;
    // ---- gather phase ----
    {
        int nloc = tid >> 4;
        int half = (tid >> 3) & 1;
        int node = rbase + nloc;
        int f = (tid & 7) * 8;         // cols [f,f+8) and [f+64,f+72)
        int beg = row_off[node], end = row_off[node + 1];
        float a0[8], a1[8];
        #pragma unroll
        for (int j = 0; j < 8; j++) { a0[j] = 0.f; a1[j] = 0.f; }
        int e = beg + half;
        for (; e + 6 < end; e += 8) {
            int2 r0 = csr[e], r1 = csr[e + 2], r2 = csr[e + 4], r3 = csr[e + 6];
            float c0 = __int_as_float(r0.y), c1 = __int_as_float(r1.y);
            float c2 = __int_as_float(r2.y), c3 = __int_as_float(r3.y);
            s16x8 v00 = *reinterpret_cast<const s16x8*>(&h0B[(size_t)r0.x * D0 + f]);
            s16x8 v01 = *reinterpret_cast<const s16x8*>(&h0B[(size_t)r0.x * D0 + f + 64]);
            s16x8 v10 = *reinterpret_cast<const s16x8*>(&h0B[(size_t)r1.x * D0 + f]);
            s16x8 v11 = *reinterpret_cast<const s16x8*>(&h0B[(size_t)r1.x * D0 + f + 64]);
            s16x8 v20 = *reinterpret_cast<const s16x8*>(&h0B[(size_t)r2.x * D0 + f]);
            s16x8 v21 = *reinterpret_cast<const s16x8*>(&h0B[(size_t)r2.x * D0 + f + 64]);
            s16x8 v30 = *reinterpret_cast<const s16x8*>(&h0B[(size_t)r3.x * D0 + f]);
            s16x8 v31 = *reinterpret_cast<const s16x8*>(&h0B[(size_t)r3.x * D0 + f + 64]);
            #pragma unroll
            for (int j = 0; j < 8; j++) {
                a0[j] += b2f((ushort)v00[j]) * c0 + b2f((ushort)v10[j]) * c1 +
                         b2f((ushort)v20[j]) * c2 + b2f((ushort)v30[j]) * c3;
                a1[j] += b2f((ushort)v01[j]) * c0 + b2f((ushort)v11[j]) * c1 +
                         b2f((ushort)v21[j]) * c2 + b2f((ushort)v31[j]) * c3;
            }
        }
        for (; e < end; e += 2) {
            int2 r = csr[e];
            float sc = __int_as_float(r.y);
            s16x8 v0 = *reinterpret_cast<const s16x8*>(&h0B[(size_t)r.x * D0 + f]);
            s16x8 v1 = *reinterpret_cast<const s16x8*>(&h0B[(size_t)r.x * D0 + f + 64]);
            #pragma unroll
            for (int j = 0; j < 8; j++) {
                a0[j] += b2f((ushort)v0[j]) * sc;
                a1[j] += b2f((ushort)v1[j]) * sc;
            }
        }
        #pragma unroll
        for (int j = 0; j < 8; j++) {
            a0[j] += __shfl_xor(a0[j], 8);
            a1[j] += __shfl_xor(a1[j], 8);
        }
        if (half == 0) {
            float si = rsq_in[node];
            s16x8 o0, o1;
            #pragma unroll
            for (int j = 0; j < 8; j++) {
                o0[j] = (short)f2b(a0[j] * si);
                o1[j] = (short)f2b(a1[j] * si);
            }
            int swz = (nloc & 15) << 4;
            int x0 = f * 2;
            *reinterpret_cast<s16x8*>(((char*)sA) + nloc * 256 + (x0 ^ swz)) = o0;
            *reinterpret_cast<s16x8*>(((char*)sA) + nloc * 256 + ((x0 + 128) ^ swz)) = o1;
        }
    }
    __syncthreads();
    // ---- MFMA phase ----
    int w = tid >> 6, lane = tid & 63, m = lane & 15, g4 = lane >> 4;
    int cb = w * 32;
    s16x8 BG[2][4], BR[2][4];
    #pragma unroll
    for (int nt = 0; nt < 2; nt++)
        #pragma unroll
        for (int j = 0; j < 4; j++) {
            BG[nt][j] = *reinterpret_cast<const s16x8*>(&WB1[(size_t)(cb + nt * 16 + m) * D0 + j * 32 + g4 * 8]);
            BR[nt][j] = *reinterpret_cast<const s16x8*>(&RWB[(size_t)(cb + nt * 16 + m) * D0 + j * 32 + g4 * 8]);
        }
    float bg[2], brv[2];
    #pragma unroll
    for (int nt = 0; nt < 2; nt++) {
        bg[nt]  = b1[cb + nt * 16 + m];
        brv[nt] = rb[cb + nt * 16 + m];
    }
    float ps[2] = {0.f, 0.f}, pq[2] = {0.f, 0.f};
    #pragma unroll
    for (int rt = 0; rt < 2; rt++) {
        int row = rt * 16 + m;
        s16x8 aA[4], aH[4];
        #pragma unroll
        for (int j = 0; j < 4; j++) {
            int boff = row * 256 + (((j * 4 + g4) * 16) ^ ((row & 15) << 4));
            aA[j] = *reinterpret_cast<const s16x8*>(((const char*)sA) + boff);
            aH[j] = *reinterpret_cast<const s16x8*>(&h0B[(size_t)(rbase + row) * D0 + j * 32 + g4 * 8]);
        }
        f32x4 accG[2], accR[2];
        #pragma unroll
        for (int nt = 0; nt < 2; nt++) {
            accG[nt] = (f32x4){0.f, 0.f, 0.f, 0.f};
            accR[nt] = (f32x4){0.f, 0.f, 0.f, 0.f};
        }
        #pragma unroll
        for (int j = 0; j < 4; j++)
            #pragma unroll
            for (int nt = 0; nt < 2; nt++) {
                accG[nt] = __builtin_amdgcn_mfma_f32_16x16x32_bf16(aA[j], BG[nt][j], accG[nt], 0, 0, 0);
                accR[nt] = __builtin_amdgcn_mfma_f32_16x16x32_bf16(aH[j], BR[nt][j], accR[nt], 0, 0, 0);
            }
        #pragma unroll
        for (int nt = 0; nt < 2; nt++) {
            int col = cb + nt * 16 + m;
            #pragma unroll
            for (int r = 0; r < 4; r++) {
                int orow = rbase + rt * 16 + g4 * 4 + r;
                float v = gelu_exact(accG[nt][r] + bg[nt]) + accR[nt][r] + brv[nt];
                t1B[(size_t)orow * D1 + col] = f2b(v);
                t1Q[(size_t)orow * D1 + col] = f2q(v);
                ps[nt] += v; pq[nt] += v * v;
            }
        }
    }
    #pragma unroll
    for (int nt = 0; nt < 2; nt++) {
        float s = ps[nt], q = pq[nt];
        s += __shfl_xor(s, 16); s += __shfl_xor(s, 32);
        q += __shfl_xor(q, 16); q += __shfl_xor(q, 32);
        if (g4 == 0) {
            int col = cb + nt * 16 + m;
            partials[(size_t)col * RBLK + blockIdx.x] = s;
            partials[(size_t)(256 + col) * RBLK + blockIdx.x] = q;
        }
    }
}

// ---------- layer2 fused: 1024 thr, 32 rows/block, shfl-batched fp8 gather, MFMA ----------
// Gather: 32 thr/node, each owns one 8-col fp8 chunk (8B); all threads walk all edges
// via shfl broadcast of the node's first 32 edge records.  [round-16 body — measured best]

__global__ __launch_bounds__(1024) void k_layer2f(
    const ushort* __restrict__ t1B, const unsigned char* __restrict__ t1Q,
    const float* __restrict__ sc1, const float* __restrict__ sh1,
    const float* __restrict__ rsq_in,
    const int* __restrict__ row_off, const int2* __restrict__ csr,
    const ushort* __restrict__ WB2, const float* __restrict__ b2,
    ushort* __restrict__ t2B, float* __restrict__ partials) {
    __shared__ ushort sA[32 * 256];
    int tid = threadIdx.x;
    int rbase = blockIdx.x * 32;
    // ---- gather phase ----
    {
        int nloc = tid >> 5;
        int l32 = tid & 31;
        int node = rbase + nloc;
        int f0 = l32 * 8;              // fp8 cols [f0, f0+8)
        int beg = row_off[node], end = row_off[node + 1];
        int deg = end - beg;
        int grp = (tid & 63) & 32;     // node's base lane within wave
        float a[8];
        #pragma unroll
        for (int j = 0; j < 8; j++) a[j] = 0.f;
        float ssum = 0.f;
        int2 my = (l32 < deg) ? csr[beg + l32] : make_int2(0, 0);
        int nb = deg < 32 ? deg : 32;
        for (int kb = 0; kb < nb; kb += 8) {
            int s[8]; float c[8];
            #pragma unroll
            for (int k2 = 0; k2 < 8; k2++) {
                s[k2] = __shfl(my.x, grp + kb + k2);
                c[k2] = __int_as_float(__shfl(my.y, grp + kb + k2));
            }
            uint2 q[8];
            #pragma unroll
            for (int k2 = 0; k2 < 8; k2++)
                q[k2] = *reinterpret_cast<const uint2*>(&t1Q[(size_t)s[k2] * D1 + f0]);
            #pragma unroll
            for (int k2 = 0; k2 < 8; k2++) {
                acc8(a, q[k2], c[k2]);
                ssum += c[k2];
            }
        }
        for (int e = beg + 32; e < end; e++) {      // essentially never
            int2 r = csr[e];
            float sc = __int_as_float(r.y);
            uint2 q = *reinterpret_cast<const uint2*>(&t1Q[(size_t)r.x * D1 + f0]);
            ssum += sc;
            acc8(a, q, sc);
        }
        float si = rsq_in[node];
        s16x8 o;
        #pragma unroll
        for (int j = 0; j < 8; j++)
            o[j] = (short)f2b((sc1[f0 + j] * a[j] + sh1[f0 + j] * ssum) * si);
        int swz = (nloc & 15) << 4;
        int boff = nloc * 512 + ((f0 * 2) ^ swz);
        *reinterpret_cast<s16x8*>(((char*)sA) + boff) = o;
    }
    __syncthreads();
    // ---- MFMA phase: 16 waves x 16 cols, 2 row-tiles each ----
    int w = tid >> 6, lane = tid & 63, m = lane & 15, g4 = lane >> 4;
    int col = w * 16 + m;
    ushort rres[2][4];
    #pragma unroll
    for (int rt = 0; rt < 2; rt++)
        #pragma unroll
        for (int r = 0; r < 4; r++)
            rres[rt][r] = t1B[(size_t)(rbase + rt * 16 + g4 * 4 + r) * D1 + col];
    s16x8 BG[8];
    #pragma unroll
    for (int j = 0; j < 8; j++)
        BG[j] = *reinterpret_cast<const s16x8*>(&WB2[(size_t)col * D1 + j * 32 + g4 * 8]);
    float bg = b2[col], a1c = sc1[col], s1c = sh1[col];
    float ps = 0.f, pq = 0.f;
    #pragma unroll
    for (int rt = 0; rt < 2; rt++) {
        int row = rt * 16 + m;
        s16x8 aA[8];
        #pragma unroll
        for (int j = 0; j < 8; j++) {
            int boff = row * 512 + (((j * 4 + g4) * 16) ^ ((row & 15) << 4));
            aA[j] = *reinterpret_cast<const s16x8*>(((const char*)sA) + boff);
        }
        f32x4 acc = (f32x4){0.f, 0.f, 0.f, 0.f};
        #pragma unroll
        for (int j = 0; j < 8; j++)
            acc = __builtin_amdgcn_mfma_f32_16x16x32_bf16(aA[j], BG[j], acc, 0, 0, 0);
        #pragma unroll
        for (int r = 0; r < 4; r++) {
            int orow = rbase + rt * 16 + g4 * 4 + r;
            float h1v = fmaf(b2f(rres[rt][r]), a1c, s1c);
            float v = gelu_exact(acc[r] + bg) + h1v;
            t2B[(size_t)orow * D1 + col] = f2b(v);
            ps += v; pq += v * v;
        }
    }
    ps += __shfl_xor(ps, 16); ps += __shfl_xor(ps, 32);
    pq += __shfl_xor(pq, 16); pq += __shfl_xor(pq, 32);
    if (g4 == 0) {
        partials[(size_t)col * RBLK + blockIdx.x] = ps;
        partials[(size_t)(256 + col) * RBLK + blockIdx.x] = pq;
    }
}

// ---------- BN reduce: one block per channel ----------

__global__ __launch_bounds__(256) void k_reduce(
    const float* __restrict__ partials, const float* __restrict__ g,
    const float* __restrict__ b, float* __restrict__ sc, float* __restrict__ sh) {
    int c = blockIdx.x;
    int t = threadIdx.x;
    const float* ps = partials + (size_t)c * RBLK;
    const float* pq = partials + (size_t)(256 + c) * RBLK;
    float s = ps[t] + ps[t + 256] + ps[t + 512] + ps[t + 768];
    float q = pq[t] + pq[t + 256] + pq[t + 512] + pq[t + 768];
    __shared__ float Ls[256], Lq[256];
    Ls[t] = s; Lq[t] = q;
    __syncthreads();
    for (int o = 128; o > 0; o >>= 1) {
        if (t < o) { Ls[t] += Ls[t + o]; Lq[t] += Lq[t + o]; }
        __syncthreads();
    }
    if (t == 0) {
        float m = Ls[0] * (1.0f / (float)N_NODES);
        float var = Lq[0] * (1.0f / (float)N_NODES) - m * m;
        float a = g[c] / sqrtf(var + BN_EPS);
        sc[c] = a;
        sh[c] = b[c] - m * a;
    }
}

// ---------- final BN apply: out = sc2*t2 + sh2  (fp32 out) ----------

__global__ __launch_bounds__(256) void k_apply(
    const ushort* __restrict__ t2B, const float* __restrict__ sc,
    const float* __restrict__ sh, float* __restrict__ out) {
    int idx = blockIdx.x * 256 + threadIdx.x;
    size_t base = (size_t)idx * 8;
    int c = (int)(base & 255);
    s16x8 v = *reinterpret_cast<const s16x8*>(&t2B[base]);
    float4 o0, o1;
    o0.x = fmaf(b2f((ushort)v[0]), sc[c + 0], sh[c + 0]);
    o0.y = fmaf(b2f((ushort)v[1]), sc[c + 1], sh[c + 1]);
    o0.z = fmaf(b2f((ushort)v[2]), sc[c + 2], sh[c + 2]);
    o0.w = fmaf(b2f((ushort)v[3]), sc[c + 3], sh[c + 3]);
    o1.x = fmaf(b2f((ushort)v[4]), sc[c + 4], sh[c + 4]);
    o1.y = fmaf(b2f((ushort)v[5]), sc[c + 5], sh[c + 5]);
    o1.z = fmaf(b2f((ushort)v[6]), sc[c + 6], sh[c + 6]);
    o1.w = fmaf(b2f((ushort)v[7]), sc[c + 7], sh[c + 7]);
    *reinterpret_cast<float4*>(&out[base]) = o0;
    *reinterpret_cast<float4*>(&out[base + 4]) = o1;
}

// ---------- launch ----------

static inline size_t align256(size_t x) { return (x + 255) & ~(size_t)255; }

extern "C" void kernel_launch(void* const* d_in, const int* in_sizes, int n_in,
                              void* d_out, int out_size, void* d_ws, size_t ws_size,
                              hipStream_t stream) {
    const float* node_feats = (const float*)d_in[0];
    const float* W_init     = (const float*)d_in[1];
    const float* gcn_w1     = (const float*)d_in[2];
    const float* gcn_b1     = (const float*)d_in[3];
    const float* res_w1     = (const float*)d_in[4];
    const float* res_b1     = (const float*)d_in[5];
    const float* bn_g1      = (const float*)d_in[6];
    const float* bn_b1      = (const float*)d_in[7];
    const float* gcn_w2     = (const float*)d_in[8];
    const float* gcn_b2     = (const float*)d_in[9];
    const float* bn_g2      = (const float*)d_in[10];
    const float* bn_b2      = (const float*)d_in[11];
    const int*   edge_src   = (const int*)d_in[12];
    const int*   edge_dst   = (const int*)d_in[13];
    float* out = (float*)d_out;

    char* p = (char*)d_ws;
    size_t off = 0;
    auto take = [&](size_t bytes) { void* r = p + off; off += align256(bytes); return r; };

    ushort* h0B   = (ushort*)take((size_t)N_NODES * D0 * 2);
    ushort* t1B   = (ushort*)take((size_t)N_NODES * D1 * 2);
    unsigned char* t1Q = (unsigned char*)take((size_t)N_NODES * D1);
    ushort* t2B   = (ushort*)take((size_t)N_NODES * D1 * 2);
    ushort* nfB   = (ushort*)take((size_t)N_NODES * KP * 2);
    ushort* WTB   = (ushort*)take((size_t)D0 * KP * 2);
    ushort* WB1   = (ushort*)take((size_t)D1 * D0 * 2);
    ushort* RWB   = (ushort*)take((size_t)D1 * D0 * 2);
    ushort* WB2   = (ushort*)take((size_t)D1 * D1 * 2);
    float*  part1 = (float*)take((size_t)2 * 256 * RBLK * 4);
    float*  part2 = (float*)take((size_t)2 * 256 * RBLK * 4);
    float*  sc1   = (float*)take(256 * 4);
    float*  sh1   = (float*)take(256 * 4);
    float*  sc2   = (float*)take(256 * 4);
    float*  sh2   = (float*)take(256 * 4);
    float*  rsq_out = (float*)take((size_t)N_NODES * 4);
    float*  rsq_in  = (float*)take((size_t)N_NODES * 4);
    int*    degi    = (int*)take((size_t)2 * N_NODES * 4);
    int*    cursor  = (int*)take((size_t)N_NODES * 4);
    int*    row_off = (int*)take((size_t)(N_NODES + 2) * 4);
    int2*   csr     = (int2*)take((size_t)E_EDGES * 8);

    hipMemsetAsync(degi, 0, (size_t)2 * N_NODES * 4, stream);

    k_front_a<<<1024 + (N_NODES * KP) / 256, 256, 0, stream>>>(
        edge_src, edge_dst, degi, node_feats, W_init, gcn_w1, res_w1, gcn_w2,
        nfB, WTB, WB1, RWB, WB2);

    k_scan_init<<<1 + N_NODES / 32, 1024, 0, stream>>>(
        degi, row_off, rsq_out, rsq_in, cursor, nfB, WTB, h0B);

    k_fill<<<E_EDGES / 512, 512, 0, stream>>>(
        edge_src, edge_dst, row_off, rsq_out, cursor, csr);

    k_layer1f<<<RBLK, 512, 0, stream>>>(h0B, rsq_in, row_off, csr,
                                        WB1, RWB, gcn_b1, res_b1, t1B, t1Q, part1);
    k_reduce<<<256, 256, 0, stream>>>(part1, bn_g1, bn_b1, sc1, sh1);

    k_layer2f<<<RBLK, 1024, 0, stream>>>(t1B, t1Q, sc1, sh1, rsq_in, row_off, csr,
                                         WB2, gcn_b2, t2B, part2);
    k_reduce<<<256, 256, 0, stream>>>(part2, bn_g2, bn_b2, sc2, sh2);

    k_apply<<<(N_NODES * D1 / 8) / 256, 256, 0, stream>>>(t2B, sc2, sh2, out);
}